// Round 1
// baseline (132.606 us; speedup 1.0000x reference)
//
#include <hip/hip_runtime.h>

// RRNN bigram scan: L=2048, B=32, BIDIR=1, D=256.
// c1_t = c1_{t-1}*f1 + u1 ; c2_t = c2_{t-1}*f2 + (eps + c1_{t-1})*u2
// u layout: [L][B][1][D][4] fp32 -> one float4 (u1,u2,f1,f2) per (t,ch).
// out layout (flat): c1s [L][B][1][D] | c2s [L][B][1][D] | c1_fin [B][D] | c2_fin [B][D]

#define LL 2048
#define BB 32
#define DD 256
#define CH (BB * DD)   // 8192 independent channels
#define PF 16          // register prefetch depth (16 outstanding dwordx4/thread)

__global__ __launch_bounds__(64, 1) void rrnn_scan_kernel(
    const float4* __restrict__ u,
    const float*  __restrict__ c1i,
    const float*  __restrict__ c2i,
    const float*  __restrict__ eps,
    float*        __restrict__ out)
{
    const int ch = blockIdx.x * 64 + threadIdx.x;   // 0..8191
    const int d  = ch & (DD - 1);

    float c1 = c1i[ch];
    float c2 = c2i[ch];
    const float e = eps[d];

    const float4* __restrict__ up = u + ch;                    // stride CH float4 per t
    float* __restrict__ o1 = out + ch;                         // stride CH floats per t
    float* __restrict__ o2 = out + (size_t)LL * CH + ch;

    // Software-pipelined register buffer: loads are independent of the
    // recurrence, so keep PF dwordx4 loads in flight at all times.
    float4 buf[PF];
#pragma unroll
    for (int i = 0; i < PF; ++i) buf[i] = up[(size_t)i * CH];

    for (int t0 = 0; t0 < LL - PF; t0 += PF) {
#pragma unroll
        for (int i = 0; i < PF; ++i) {
            const float4 x = buf[i];
            buf[i] = up[(size_t)(t0 + PF + i) * CH];           // prefetch t+PF
            const float c1n = fmaf(c1, x.z, x.x);
            const float c2n = fmaf(c2, x.w, (e + c1) * x.y);
            c1 = c1n;
            c2 = c2n;
            o1[(size_t)(t0 + i) * CH] = c1;
            o2[(size_t)(t0 + i) * CH] = c2;
        }
    }
    // tail: last PF steps, no prefetch
#pragma unroll
    for (int i = 0; i < PF; ++i) {
        const float4 x = buf[i];
        const float c1n = fmaf(c1, x.z, x.x);
        const float c2n = fmaf(c2, x.w, (e + c1) * x.y);
        c1 = c1n;
        c2 = c2n;
        o1[(size_t)(LL - PF + i) * CH] = c1;
        o2[(size_t)(LL - PF + i) * CH] = c2;
    }

    // finals
    out[(size_t)2 * LL * CH + ch]      = c1;
    out[(size_t)2 * LL * CH + CH + ch] = c2;
}

extern "C" void kernel_launch(void* const* d_in, const int* in_sizes, int n_in,
                              void* d_out, int out_size, void* d_ws, size_t ws_size,
                              hipStream_t stream) {
    const float4* u   = (const float4*)d_in[0];   // L*B*1*D*4 fp32 = L*CH float4
    const float*  c1i = (const float*)d_in[1];    // B*D
    const float*  c2i = (const float*)d_in[2];    // B*D
    const float*  eps = (const float*)d_in[3];    // D
    float* out = (float*)d_out;

    rrnn_scan_kernel<<<CH / 64, 64, 0, stream>>>(u, c1i, c2i, eps, out);
}

// Round 3
// 125.162 us; speedup vs baseline: 1.0595x; 1.0595x over previous
//
#include <hip/hip_runtime.h>

// RRNN bigram scan: L=2048, B=32, BIDIR=1, D=256.
// c1_t = c1_{t-1}*f1 + u1 ; c2_t = c2_{t-1}*f2 + (eps + c1_{t-1})*u2
// u layout: [L][B][1][D][4] fp32 -> one float4 (u1,u2,f1,f2) per (t,ch).
// out layout (flat): c1s [L][B][1][D] | c2s [L][B][1][D] | c1_fin [B][D] | c2_fin [B][D]
//
// R1/R2: PF 16 -> 32 (deep register prefetch pipeline; measured effective
// latency ~2460 cyc needs ~32 KB in flight per wave), nontemporal hints.
// R2 fix: ext_vector_type float4 (HIP_vector_type struct rejected by
// __builtin_nontemporal_load).

#define LL 2048
#define BB 32
#define DD 256
#define CH (BB * DD)   // 8192 independent channels
#define PF 32          // register prefetch depth (32 outstanding dwordx4/thread)

typedef float f4 __attribute__((ext_vector_type(4)));

__global__ __launch_bounds__(64, 1) void rrnn_scan_kernel(
    const f4*    __restrict__ u,
    const float* __restrict__ c1i,
    const float* __restrict__ c2i,
    const float* __restrict__ eps,
    float*       __restrict__ out)
{
    const int ch = blockIdx.x * 64 + threadIdx.x;   // 0..8191
    const int d  = ch & (DD - 1);

    float c1 = c1i[ch];
    float c2 = c2i[ch];
    const float e = eps[d];

    const f4* __restrict__ up = u + ch;                        // stride CH f4 per t
    float* __restrict__ o1 = out + ch;                         // stride CH floats per t
    float* __restrict__ o2 = out + (size_t)LL * CH + ch;

    // Software-pipelined register buffer: loads are independent of the
    // recurrence, so keep PF dwordx4 loads in flight at all times.
    f4 buf[PF];
#pragma unroll
    for (int i = 0; i < PF; ++i)
        buf[i] = __builtin_nontemporal_load(&up[(size_t)i * CH]);

    for (int t0 = 0; t0 < LL - PF; t0 += PF) {
#pragma unroll
        for (int i = 0; i < PF; ++i) {
            const f4 x = buf[i];
            buf[i] = __builtin_nontemporal_load(&up[(size_t)(t0 + PF + i) * CH]); // prefetch t+PF
            const float c1n = fmaf(c1, x.z, x.x);
            const float c2n = fmaf(c2, x.w, (e + c1) * x.y);
            c1 = c1n;
            c2 = c2n;
            __builtin_nontemporal_store(c1, &o1[(size_t)(t0 + i) * CH]);
            __builtin_nontemporal_store(c2, &o2[(size_t)(t0 + i) * CH]);
        }
    }
    // tail: last PF steps, no prefetch
#pragma unroll
    for (int i = 0; i < PF; ++i) {
        const f4 x = buf[i];
        const float c1n = fmaf(c1, x.z, x.x);
        const float c2n = fmaf(c2, x.w, (e + c1) * x.y);
        c1 = c1n;
        c2 = c2n;
        __builtin_nontemporal_store(c1, &o1[(size_t)(LL - PF + i) * CH]);
        __builtin_nontemporal_store(c2, &o2[(size_t)(LL - PF + i) * CH]);
    }

    // finals
    out[(size_t)2 * LL * CH + ch]      = c1;
    out[(size_t)2 * LL * CH + CH + ch] = c2;
}

extern "C" void kernel_launch(void* const* d_in, const int* in_sizes, int n_in,
                              void* d_out, int out_size, void* d_ws, size_t ws_size,
                              hipStream_t stream) {
    const f4*    u   = (const f4*)d_in[0];        // L*B*1*D*4 fp32 = L*CH f4
    const float* c1i = (const float*)d_in[1];     // B*D
    const float* c2i = (const float*)d_in[2];     // B*D
    const float* eps = (const float*)d_in[3];     // D
    float* out = (float*)d_out;

    rrnn_scan_kernel<<<CH / 64, 64, 0, stream>>>(u, c1i, c2i, eps, out);
}

// Round 4
// 65.616 us; speedup vs baseline: 2.0209x; 1.9075x over previous
//
#include <hip/hip_runtime.h>

// RRNN bigram scan: L=2048, B=32, BIDIR=1, D=256.
// c1_t = c1_{t-1}*f1 + u1 ; c2_t = c2_{t-1}*f2 + (eps + c1_{t-1})*u2
// u layout: [L][B][1][D][4] fp32 -> one float4 (u1,u2,f1,f2) per (t,ch).
// out: c1s [L][CH] | c2s [L][CH] | c1_fin [CH] | c2_fin [CH]
//
// R3: wave-specialized producer/consumer. The single-wave version was
// vmcnt-window-capped (3 vmem ops/step, in-order retire, <=63 outstanding
// => ~21-step window ~ 3090 cyc = measured loaded latency). Split roles:
//   wave0 loader : global_load_lds only (1 vmem/step, 2-chunk pipeline,
//                  counted vmcnt, NEVER drained to 0 in steady state)
//   wave1 compute: ds_read_b128 -> 4 FMA -> ds_write_b64 (no vmem at all)
//   wave2 storer : ds_read_b64 -> 2 nontemporal stores (fire-and-forget)
// Raw s_barrier + counted waits (syncthreads would drain the loader).

#define LL 2048
#define CH 8192
#define CHUNK 32
#define NCHK (LL / CHUNK)   // 64

typedef float f4 __attribute__((ext_vector_type(4)));
typedef float f2 __attribute__((ext_vector_type(2)));

__device__ __forceinline__ void gload_lds16(const void* g, void* l) {
    __builtin_amdgcn_global_load_lds(
        (const __attribute__((address_space(1))) unsigned int*)g,
        (__attribute__((address_space(3))) unsigned int*)l, 16, 0, 0);
}

__global__ __launch_bounds__(192, 1) void rrnn_scan_kernel(
    const f4*    __restrict__ u,
    const float* __restrict__ c1i,
    const float* __restrict__ c2i,
    const float* __restrict__ eps,
    float*       __restrict__ out)
{
    __shared__ f4 s_in[3][CHUNK][64];    // 96 KB, triple-buffered input
    __shared__ f2 s_res[2][CHUNK][64];   // 32 KB, double-buffered results

    const int lane = threadIdx.x & 63;
    const int wv   = threadIdx.x >> 6;
    const int ch   = blockIdx.x * 64 + lane;

    if (wv == 0) {
        // ---------------- loader ----------------
        const f4* __restrict__ up = u + ch;
        // prologue: issue chunks 0,1
        for (int c = 0; c < 2; ++c) {
#pragma unroll
            for (int i = 0; i < CHUNK; ++i)
                gload_lds16(&up[(size_t)(c * CHUNK + i) * CH], &s_in[c][i][lane]);
        }
        asm volatile("s_waitcnt vmcnt(32)" ::: "memory");   // chunk 0 complete
        __builtin_amdgcn_s_barrier();                       // barrier #0: in[0] ready
        int b2 = 2;  // (k+2) % 3
        for (int k = 0; k < NCHK; ++k) {
            const int c = k + 2;
            if (c < NCHK) {
#pragma unroll
                for (int i = 0; i < CHUNK; ++i)
                    gload_lds16(&up[(size_t)(c * CHUNK + i) * CH], &s_in[b2][i][lane]);
                asm volatile("s_waitcnt vmcnt(32)" ::: "memory");  // chunk k+1 done
            } else {
                asm volatile("s_waitcnt vmcnt(0)" ::: "memory");   // drain tail
            }
            __builtin_amdgcn_s_barrier();   // barrier #k+1: in[(k+1)%3] ready
            b2 = (b2 == 2) ? 0 : b2 + 1;
        }
    } else if (wv == 1) {
        // ---------------- compute ----------------
        float c1 = c1i[ch];
        float c2 = c2i[ch];
        const float e = eps[ch & 255];
        __builtin_amdgcn_s_barrier();                       // barrier #0
        asm volatile("" ::: "memory");
        int b = 0;  // k % 3
        for (int k = 0; k < NCHK; ++k) {
#pragma unroll
            for (int i = 0; i < CHUNK; ++i) {
                const f4 x = s_in[b][i][lane];
                const float c1n = fmaf(c1, x.z, x.x);
                const float c2n = fmaf(c2, x.w, (e + c1) * x.y);
                c1 = c1n;
                c2 = c2n;
                s_res[k & 1][i][lane] = f2{c1, c2};
            }
            asm volatile("s_waitcnt lgkmcnt(0)" ::: "memory");  // res writes visible
            __builtin_amdgcn_s_barrier();   // barrier #k+1: res[k&1] ready
            asm volatile("" ::: "memory");
            b = (b == 2) ? 0 : b + 1;
        }
        // finals
        out[(size_t)2 * LL * CH + ch]      = c1;
        out[(size_t)2 * LL * CH + CH + ch] = c2;
    } else {
        // ---------------- storer ----------------
        float* __restrict__ o1 = out + ch;
        float* __restrict__ o2 = out + (size_t)LL * CH + ch;
        __builtin_amdgcn_s_barrier();                       // barrier #0
        for (int k = 0; k < NCHK; ++k) {
            __builtin_amdgcn_s_barrier();   // barrier #k+1: res[k&1] ready
            asm volatile("" ::: "memory");
#pragma unroll
            for (int i = 0; i < CHUNK; ++i) {
                const f2 v = s_res[k & 1][i][lane];
                __builtin_nontemporal_store(v.x, &o1[(size_t)(k * CHUNK + i) * CH]);
                __builtin_nontemporal_store(v.y, &o2[(size_t)(k * CHUNK + i) * CH]);
            }
        }
    }
}

extern "C" void kernel_launch(void* const* d_in, const int* in_sizes, int n_in,
                              void* d_out, int out_size, void* d_ws, size_t ws_size,
                              hipStream_t stream) {
    const f4*    u   = (const f4*)d_in[0];        // L*CH f4
    const float* c1i = (const float*)d_in[1];     // B*D
    const float* c2i = (const float*)d_in[2];     // B*D
    const float* eps = (const float*)d_in[3];     // D
    float* out = (float*)d_out;

    rrnn_scan_kernel<<<CH / 64, 192, 0, stream>>>(u, c1i, c2i, eps, out);
}